// Round 7
// baseline (813.718 us; speedup 1.0000x reference)
//
#include <hip/hip_runtime.h>
#include <math.h>

// flash-decode, GQA paged KV. R=4, B=16, Hq=32, Hk=8 (G=4), D=128, P=8192,
// PAGE=1, M=2048.
// Storage model (derived from 6 rounds of black-box forensics):
//   q/k_cache/v_cache: FLOAT32 on device (harness up-converts fp16 inputs;
//     evidence: exact-512 cap in rounds 1/2 = fp16 decode of f32 low halves
//     {k<<13}; kc[0]=0x8000 from round-5 diag; clamp-hit in round 6).
//   lens/block_table: int32.  d_out: float32.
// Runtime insurance: low-13-bits-zero census distinguishes f32-from-fp16
// (always zero) from any true 16-bit storage (never zero); fp16/bf16
// u16-decode fallbacks retained.

typedef unsigned short u16;
typedef u16 u16x8 __attribute__((ext_vector_type(8)));
typedef float f32x4 __attribute__((ext_vector_type(4)));

#define R_ 4
#define B_ 16
#define HQ_ 32
#define HK_ 8
#define G_ 4
#define D_ 128
#define P_ 8192
#define M_ 2048
#define SCALE_F 0.08838834764831845f

// ws[0]=dt (0=f32, 1=fp16 bits, 2=bf16 bits), ws[1]=lens mode, ws[2]=bt mode
__global__ void sniff_kernel(const unsigned* kc32, const int* lens,
                             const int* bt, int* ws) {
  if (threadIdx.x != 0 || blockIdx.x != 0) return;
  int cnt = 0;
  for (int i = 0; i < 64; ++i)
    if ((kc32[i] & 0x1FFFu) == 0u) ++cnt;  // fp16->f32 conversion signature
  int dt;
  if (cnt >= 56) {
    dt = 0;
  } else {
    const u16* u = (const u16*)kc32;
    int c_low = 0;
    for (int i = 0; i < 4096; ++i) {
      unsigned v = u[i] & 0x7FFF;
      unsigned e = (v >> 10) & 31;
      if (v && e <= 13) ++c_low;  // fp16 N(0,1): ~38%; bf16: ~0
    }
    dt = (c_low >= 64) ? 1 : 2;
  }
  ws[0] = dt;
  int l0 = lens[0];
  ws[1] = (l0 >= 1 && l0 <= M_) ? 0 : 1;  // 1 -> float-coded ints
  int b0 = bt[0];
  ws[2] = (b0 >= 0 && b0 < P_) ? 0 : 1;
}

__device__ __forceinline__ float dec16(u16 u, int dt) {
  if (dt == 1) {
    _Float16 h;
    __builtin_memcpy(&h, &u, 2);
    return (float)h;
  }
  unsigned x = ((unsigned)u) << 16;
  float f;
  __builtin_memcpy(&f, &x, 4);
  return f;
}

// load 8 consecutive elements starting at element offset `off`
__device__ __forceinline__ void load8(const void* base, size_t off, int dt,
                                      float o[8]) {
  if (dt == 0) {
    const float* p = (const float*)base + off;
    f32x4 a = *(const f32x4*)p;
    f32x4 b = *(const f32x4*)(p + 4);
#pragma unroll
    for (int j = 0; j < 4; ++j) { o[j] = a[j]; o[4 + j] = b[j]; }
  } else {
    const u16* p = (const u16*)base + off;
    u16x8 v = *(const u16x8*)p;
#pragma unroll
    for (int j = 0; j < 8; ++j) o[j] = dec16(v[j], dt);
  }
}

__device__ __forceinline__ int dec_int(int raw, int mode) {
  return mode == 0 ? raw : (int)__int_as_float(raw);
}

__global__ __launch_bounds__(256) void fd_mono(
    const void* __restrict__ q, const void* __restrict__ kc,
    const void* __restrict__ vc, const int* __restrict__ lens,
    const int* __restrict__ bt, const int* __restrict__ ws,
    float* __restrict__ out) {
  const int dt = ws[0];
  const int lmode = ws[1];
  const int bmode = ws[2];

  const int hk = blockIdx.x % HK_;
  const int b = blockIdx.x / HK_;
  const int lane = threadIdx.x & 63;
  const int g = threadIdx.x >> 6;  // wave id == GQA sub-head
  const int tg = lane >> 4;        // token sub-slot 0..3
  const int ds = (lane & 15) * 8;  // dim slice [ds, ds+8)

  float qf[8];
  load8(q, (size_t)(b * HQ_ + hk * G_ + g) * D_ + ds, dt, qf);

  float m = -INFINITY, l = 0.f, acc[8];
#pragma unroll
  for (int j = 0; j < 8; ++j) acc[j] = 0.f;

  for (int r = 0; r < R_; ++r) {
    int kvlen = dec_int(lens[r * B_ + b], lmode);
    if (kvlen < 0) kvlen = 0;
    if (kvlen > M_) kvlen = M_;
    const int* btrow = bt + (r * B_ + b) * M_;
    const size_t rbase = (size_t)r * P_ * HK_ * D_ + (size_t)hk * D_ + ds;

    for (int t0 = 0; t0 < kvlen; t0 += 8) {
      int ta = t0 + tg;
      int tb = t0 + 4 + tg;
      bool va = ta < kvlen;
      bool vbv = tb < kvlen;
      int pga = dec_int(btrow[va ? ta : 0], bmode);
      int pgb = dec_int(btrow[vbv ? tb : 0], bmode);
      pga = pga < 0 ? 0 : (pga >= P_ ? P_ - 1 : pga);
      pgb = pgb < 0 ? 0 : (pgb >= P_ ? P_ - 1 : pgb);
      size_t offa = rbase + (size_t)pga * (HK_ * D_);
      size_t offb = rbase + (size_t)pgb * (HK_ * D_);

      float ka[8], kb8[8], wa[8], wb[8];
      load8(kc, offa, dt, ka);
      load8(kc, offb, dt, kb8);
      load8(vc, offa, dt, wa);
      load8(vc, offb, dt, wb);

      float da = 0.f, db = 0.f;
#pragma unroll
      for (int j = 0; j < 8; ++j) {
        da += qf[j] * ka[j];
        db += qf[j] * kb8[j];
      }
      da += __shfl_xor(da, 1); db += __shfl_xor(db, 1);
      da += __shfl_xor(da, 2); db += __shfl_xor(db, 2);
      da += __shfl_xor(da, 4); db += __shfl_xor(db, 4);
      da += __shfl_xor(da, 8); db += __shfl_xor(db, 8);

      float sa = va ? da * SCALE_F : -INFINITY;
      float sb = vbv ? db * SCALE_F : -INFINITY;

      float mt = fmaxf(sa, sb);
      mt = fmaxf(mt, __shfl_xor(mt, 16));
      mt = fmaxf(mt, __shfl_xor(mt, 32));

      float mn = fmaxf(m, mt);
      if (mn == -INFINITY) continue;
      float sc = (m == -INFINITY) ? 0.f : __expf(m - mn);
      float pa = (sa == -INFINITY) ? 0.f : __expf(sa - mn);
      float pb = (sb == -INFINITY) ? 0.f : __expf(sb - mn);
      m = mn;
      l = l * sc + pa + pb;
#pragma unroll
      for (int j = 0; j < 8; ++j)
        acc[j] = acc[j] * sc + pa * wa[j] + pb * wb[j];
    }
  }

  l += __shfl_xor(l, 16);
  l += __shfl_xor(l, 32);
#pragma unroll
  for (int j = 0; j < 8; ++j) {
    acc[j] += __shfl_xor(acc[j], 16);
    acc[j] += __shfl_xor(acc[j], 32);
  }

  if (lane < 16) {
    float inv = (l > 0.f) ? 1.0f / l : 0.f;
#pragma unroll
    for (int j = 0; j < 8; ++j) {
      float v = acc[j] * inv;
      v = fminf(fmaxf(v, -1.f), 1.f);  // diagnostic backstop; |ref| <= 0.2
      out[(size_t)(b * HQ_ + hk * G_ + g) * D_ + ds + j] = v;
    }
  }
}

extern "C" void kernel_launch(void* const* d_in, const int* in_sizes, int n_in,
                              void* d_out, int out_size, void* d_ws,
                              size_t ws_size, hipStream_t stream) {
  const void* q = d_in[0];
  const void* kc = d_in[1];
  const void* vc = d_in[2];
  const int* lens = (const int*)d_in[3];
  const int* bt = (const int*)d_in[4];
  float* out = (float*)d_out;
  int* ws = (int*)d_ws;

  sniff_kernel<<<1, 1, 0, stream>>>((const unsigned*)kc, lens, bt, ws);
  fd_mono<<<B_ * HK_, 256, 0, stream>>>(q, kc, vc, lens, bt, ws, out);
}

// Round 8
// 137.516 us; speedup vs baseline: 5.9172x; 5.9172x over previous
//
#include <hip/hip_runtime.h>
#include <math.h>

// flash-decode, GQA paged KV. R=4, B=16, Hq=32, Hk=8 (G=4), D=128, P=8192,
// PAGE=1, M=2048.
// Storage (confirmed round 7): q/k_cache/v_cache are FLOAT32 on device
// (harness up-converts the fp16 reference tensors); lens/bt int32; out f32.
//
// Round 8: split-KV for occupancy. fd_partial: R*B*Hk*S blocks (S=16 ->
// 8192 blocks, 32/CU), 4 waves/block = 4 GQA heads, ~64-token chunks,
// fp32 partials (m,l,o) in d_ws. fd_reduce: LSE-weighted combine.

typedef float f32x4 __attribute__((ext_vector_type(4)));

#define R_ 4
#define B_ 16
#define HQ_ 32
#define HK_ 8
#define G_ 4
#define D_ 128
#define P_ 8192
#define M_ 2048
#define SCALE_F 0.08838834764831845f

__device__ __forceinline__ void load8f(const float* p, float o[8]) {
  f32x4 a = *(const f32x4*)p;
  f32x4 b = *(const f32x4*)(p + 4);
#pragma unroll
  for (int j = 0; j < 4; ++j) { o[j] = a[j]; o[4 + j] = b[j]; }
}

// ---------------- kernel 1: per-(r,b,hk,split) partials ----------------
__global__ __launch_bounds__(256) void fd_partial(
    const float* __restrict__ q, const float* __restrict__ kc,
    const float* __restrict__ vc, const int* __restrict__ lens,
    const int* __restrict__ bt, float* __restrict__ ws_m,
    float* __restrict__ ws_l, float* __restrict__ ws_o, int S) {
  const int idx = blockIdx.x;
  const int s = idx % S;
  const int hk = (idx / S) % HK_;
  const int b = (idx / (S * HK_)) % B_;
  const int r = idx / (S * HK_ * B_);

  const int lane = threadIdx.x & 63;
  const int g = threadIdx.x >> 6;  // wave id == GQA sub-head
  const int tg = lane >> 4;        // token sub-slot 0..3
  const int ds = (lane & 15) * 8;  // dim slice [ds, ds+8)

  float qf[8];
  load8f(q + (size_t)(b * HQ_ + hk * G_ + g) * D_ + ds, qf);

  int kvlen = lens[r * B_ + b];
  if (kvlen < 0) kvlen = 0;
  if (kvlen > M_) kvlen = M_;
  const int chunk = (kvlen + S - 1) / S;
  const int t0 = s * chunk;
  int t1 = t0 + chunk;
  if (t1 > kvlen) t1 = kvlen;

  const int* btrow = bt + (r * B_ + b) * M_;
  const float* kb = kc + (size_t)r * P_ * HK_ * D_ + (size_t)hk * D_ + ds;
  const float* vb = vc + (size_t)r * P_ * HK_ * D_ + (size_t)hk * D_ + ds;

  float m = -INFINITY, l = 0.f, acc[8];
#pragma unroll
  for (int j = 0; j < 8; ++j) acc[j] = 0.f;

  for (int t = t0; t < t1; t += 8) {
    int ta = t + tg;
    int tb = t + 4 + tg;
    bool va = ta < t1;
    bool vbv = tb < t1;
    int pga = btrow[va ? ta : t0];
    int pgb = btrow[vbv ? tb : t0];
    pga = pga < 0 ? 0 : (pga >= P_ ? P_ - 1 : pga);
    pgb = pgb < 0 ? 0 : (pgb >= P_ ? P_ - 1 : pgb);
    size_t offa = (size_t)pga * (HK_ * D_);
    size_t offb = (size_t)pgb * (HK_ * D_);

    float ka[8], kb8[8], wa[8], wb[8];
    load8f(kb + offa, ka);
    load8f(kb + offb, kb8);
    load8f(vb + offa, wa);
    load8f(vb + offb, wb);

    float da = 0.f, db = 0.f;
#pragma unroll
    for (int j = 0; j < 8; ++j) {
      da += qf[j] * ka[j];
      db += qf[j] * kb8[j];
    }
    da += __shfl_xor(da, 1); db += __shfl_xor(db, 1);
    da += __shfl_xor(da, 2); db += __shfl_xor(db, 2);
    da += __shfl_xor(da, 4); db += __shfl_xor(db, 4);
    da += __shfl_xor(da, 8); db += __shfl_xor(db, 8);

    float sa = va ? da * SCALE_F : -INFINITY;
    float sb = vbv ? db * SCALE_F : -INFINITY;

    float mt = fmaxf(sa, sb);
    mt = fmaxf(mt, __shfl_xor(mt, 16));
    mt = fmaxf(mt, __shfl_xor(mt, 32));

    float mn = fmaxf(m, mt);
    if (mn == -INFINITY) continue;
    float sc = (m == -INFINITY) ? 0.f : __expf(m - mn);
    float pa = (sa == -INFINITY) ? 0.f : __expf(sa - mn);
    float pb = (sb == -INFINITY) ? 0.f : __expf(sb - mn);
    m = mn;
    l = l * sc + pa + pb;
#pragma unroll
    for (int j = 0; j < 8; ++j) acc[j] = acc[j] * sc + pa * wa[j] + pb * wb[j];
  }

  // sum partials across the 4 token slots (m already wave-uniform)
  l += __shfl_xor(l, 16);
  l += __shfl_xor(l, 32);
#pragma unroll
  for (int j = 0; j < 8; ++j) {
    acc[j] += __shfl_xor(acc[j], 16);
    acc[j] += __shfl_xor(acc[j], 32);
  }

  const int rec = blockIdx.x;  // == ((r*B+b)*HK + hk)*S + s
  if (lane < 16) {
#pragma unroll
    for (int j = 0; j < 8; ++j)
      ws_o[((size_t)rec * G_ + g) * D_ + ds + j] = acc[j];
    if (lane == 0) {
      ws_m[rec * G_ + g] = m;
      ws_l[rec * G_ + g] = l;
    }
  }
}

// ---------------- kernel 2: LSE-weighted combine over R*S ----------------
__global__ __launch_bounds__(128) void fd_reduce(
    const float* __restrict__ ws_m, const float* __restrict__ ws_l,
    const float* __restrict__ ws_o, float* __restrict__ out, int S) {
  const int row = blockIdx.x;  // (b*HK + hk)*G + g
  const int g = row % G_;
  const int hk = (row / G_) % HK_;
  const int b = row / (G_ * HK_);
  const int d = threadIdx.x;

  float mf = -INFINITY;
  for (int r = 0; r < R_; ++r)
    for (int s = 0; s < S; ++s) {
      int rec = ((r * B_ + b) * HK_ + hk) * S + s;
      mf = fmaxf(mf, ws_m[rec * G_ + g]);
    }
  float of = 0.f, lf = 0.f;
  for (int r = 0; r < R_; ++r)
    for (int s = 0; s < S; ++s) {
      int rec = ((r * B_ + b) * HK_ + hk) * S + s;
      float wm = ws_m[rec * G_ + g];
      if (wm == -INFINITY) continue;
      float wt = __expf(wm - mf);
      of += wt * ws_o[((size_t)rec * G_ + g) * D_ + d];
      lf += wt * ws_l[rec * G_ + g];
    }
  out[(size_t)(b * HQ_ + hk * G_ + g) * D_ + d] = of / lf;
}

// ---------------- fallback: monolithic (tiny workspace) ----------------
__global__ __launch_bounds__(256) void fd_mono(
    const float* __restrict__ q, const float* __restrict__ kc,
    const float* __restrict__ vc, const int* __restrict__ lens,
    const int* __restrict__ bt, float* __restrict__ out) {
  const int hk = blockIdx.x % HK_;
  const int b = blockIdx.x / HK_;
  const int lane = threadIdx.x & 63;
  const int g = threadIdx.x >> 6;
  const int tg = lane >> 4;
  const int ds = (lane & 15) * 8;

  float qf[8];
  load8f(q + (size_t)(b * HQ_ + hk * G_ + g) * D_ + ds, qf);

  float m = -INFINITY, l = 0.f, acc[8];
#pragma unroll
  for (int j = 0; j < 8; ++j) acc[j] = 0.f;

  for (int r = 0; r < R_; ++r) {
    int kvlen = lens[r * B_ + b];
    if (kvlen < 0) kvlen = 0;
    if (kvlen > M_) kvlen = M_;
    const int* btrow = bt + (r * B_ + b) * M_;
    const float* kb = kc + (size_t)r * P_ * HK_ * D_ + (size_t)hk * D_ + ds;
    const float* vb = vc + (size_t)r * P_ * HK_ * D_ + (size_t)hk * D_ + ds;

    for (int t = 0; t < kvlen; t += 8) {
      int ta = t + tg;
      int tb = t + 4 + tg;
      bool va = ta < kvlen;
      bool vbv = tb < kvlen;
      int pga = btrow[va ? ta : 0];
      int pgb = btrow[vbv ? tb : 0];
      pga = pga < 0 ? 0 : (pga >= P_ ? P_ - 1 : pga);
      pgb = pgb < 0 ? 0 : (pgb >= P_ ? P_ - 1 : pgb);
      size_t offa = (size_t)pga * (HK_ * D_);
      size_t offb = (size_t)pgb * (HK_ * D_);
      float ka[8], kb8[8], wa[8], wb[8];
      load8f(kb + offa, ka);
      load8f(kb + offb, kb8);
      load8f(vb + offa, wa);
      load8f(vb + offb, wb);

      float da = 0.f, db = 0.f;
#pragma unroll
      for (int j = 0; j < 8; ++j) {
        da += qf[j] * ka[j];
        db += qf[j] * kb8[j];
      }
      da += __shfl_xor(da, 1); db += __shfl_xor(db, 1);
      da += __shfl_xor(da, 2); db += __shfl_xor(db, 2);
      da += __shfl_xor(da, 4); db += __shfl_xor(db, 4);
      da += __shfl_xor(da, 8); db += __shfl_xor(db, 8);

      float sa = va ? da * SCALE_F : -INFINITY;
      float sb = vbv ? db * SCALE_F : -INFINITY;

      float mt = fmaxf(sa, sb);
      mt = fmaxf(mt, __shfl_xor(mt, 16));
      mt = fmaxf(mt, __shfl_xor(mt, 32));

      float mn = fmaxf(m, mt);
      if (mn == -INFINITY) continue;
      float sc = (m == -INFINITY) ? 0.f : __expf(m - mn);
      float pa = (sa == -INFINITY) ? 0.f : __expf(sa - mn);
      float pb = (sb == -INFINITY) ? 0.f : __expf(sb - mn);
      m = mn;
      l = l * sc + pa + pb;
#pragma unroll
      for (int j = 0; j < 8; ++j)
        acc[j] = acc[j] * sc + pa * wa[j] + pb * wb[j];
    }
  }

  l += __shfl_xor(l, 16);
  l += __shfl_xor(l, 32);
#pragma unroll
  for (int j = 0; j < 8; ++j) {
    acc[j] += __shfl_xor(acc[j], 16);
    acc[j] += __shfl_xor(acc[j], 32);
  }

  if (lane < 16) {
    float inv = (l > 0.f) ? 1.0f / l : 0.f;
#pragma unroll
    for (int j = 0; j < 8; ++j)
      out[(size_t)(b * HQ_ + hk * G_ + g) * D_ + ds + j] = acc[j] * inv;
  }
}

extern "C" void kernel_launch(void* const* d_in, const int* in_sizes, int n_in,
                              void* d_out, int out_size, void* d_ws,
                              size_t ws_size, hipStream_t stream) {
  const float* q = (const float*)d_in[0];
  const float* kc = (const float*)d_in[1];
  const float* vc = (const float*)d_in[2];
  const int* lens = (const int*)d_in[3];
  const int* bt = (const int*)d_in[4];
  float* out = (float*)d_out;

  auto need = [](int s) {
    return (size_t)R_ * B_ * HK_ * s * (size_t)(2 * G_ + G_ * D_) *
           sizeof(float);
  };
  int S = 16;
  while (S > 1 && need(S) > ws_size) S >>= 1;

  if (need(S) <= ws_size) {
    const int nrec = R_ * B_ * HK_ * S;
    float* ws_m = (float*)d_ws;
    float* ws_l = ws_m + (size_t)nrec * G_;
    float* ws_o = ws_l + (size_t)nrec * G_;
    fd_partial<<<nrec, 256, 0, stream>>>(q, kc, vc, lens, bt, ws_m, ws_l,
                                         ws_o, S);
    fd_reduce<<<B_ * HK_ * G_, 128, 0, stream>>>(ws_m, ws_l, ws_o, out, S);
  } else {
    fd_mono<<<B_ * HK_, 256, 0, stream>>>(q, kc, vc, lens, bt, out);
  }
}